// Round 4
// baseline (396.775 us; speedup 1.0000x reference)
//
#include <hip/hip_runtime.h>

#define N_NODES 100000
#define N_EDGES 1600000
#define HID 32
#define BN_EPS 1e-5f

// ---------------- kernels ----------------

// 1 thread per edge: in-degree histogram (int atomics)
__global__ void count_kernel(const int* __restrict__ dst, int* __restrict__ cnt) {
    int e = blockIdx.x * blockDim.x + threadIdx.x;
    if (e < N_EDGES) atomicAdd(&cnt[dst[e]], 1);
}

// per node: xd[n] = (x_n * rd_n, rd_n); S4 initialized with the self-loop term xd[n]
__global__ void xd_kernel(const float* __restrict__ x, const int* __restrict__ cnt,
                          float4* __restrict__ xd, float4* __restrict__ S4) {
    int n = blockIdx.x * blockDim.x + threadIdx.x;
    if (n >= N_NODES) return;
    float rd = rsqrtf(1.0f + (float)cnt[n]);
    float4 v = make_float4(x[3 * n] * rd, x[3 * n + 1] * rd, x[3 * n + 2] * rd, rd);
    xd[n] = v;
    S4[n] = v;   // self contribution: agg gets rd_d * (xd_d . W) = h_d / deg_d  ✓
}

// 1 thread per edge: S[dst] += xd[src]  (3 float atomics; .w untouched, holds rd_dst)
__global__ void scatter_kernel(const int* __restrict__ src, const int* __restrict__ dst,
                               const float4* __restrict__ xd, float4* __restrict__ S4) {
    int e = blockIdx.x * blockDim.x + threadIdx.x;
    if (e >= N_EDGES) return;
    int s = src[e], d = dst[e];
    float4 v = xd[s];
    float* p = (float*)&S4[d];
    atomicAdd(p + 0, v.x);
    atomicAdd(p + 1, v.y);
    atomicAdd(p + 2, v.z);
}

// 9-scalar BN sufficient statistics over a = rd*S (3-vector per node):
// m1 (3) and upper-triangular second moment M (6)
__global__ void stats_kernel(const float4* __restrict__ S4, float* __restrict__ stats) {
    __shared__ float ls[4][9];
    int tid = threadIdx.x;
    int n = blockIdx.x * blockDim.x + tid;
    float st[9];
#pragma unroll
    for (int q = 0; q < 9; ++q) st[q] = 0.f;
    if (n < N_NODES) {
        float4 s = S4[n];
        float ax = s.w * s.x, ay = s.w * s.y, az = s.w * s.z;
        st[0] = ax; st[1] = ay; st[2] = az;
        st[3] = ax * ax; st[4] = ax * ay; st[5] = ax * az;
        st[6] = ay * ay; st[7] = ay * az; st[8] = az * az;
    }
    for (int m = 1; m < 64; m <<= 1) {
#pragma unroll
        for (int q = 0; q < 9; ++q) st[q] += __shfl_xor(st[q], m);
    }
    int wave = tid >> 6;
    if ((tid & 63) == 0) {
#pragma unroll
        for (int q = 0; q < 9; ++q) ls[wave][q] = st[q];
    }
    __syncthreads();
    if (tid < 9) {
        float s = ls[0][tid] + ls[1][tid] + ls[2][tid] + ls[3][tid];
        atomicAdd(&stats[tid], s);
    }
}

// fold BN scale/shift into W and b: cbuf = {W0*sc, W1*sc, W2*sc, b*sc + sh}
__global__ void finalize_kernel(const float* __restrict__ stats, const float* __restrict__ W,
                                const float* __restrict__ b, const float* __restrict__ gamma,
                                const float* __restrict__ beta, float* __restrict__ cbuf) {
    int c = threadIdx.x;
    if (c >= HID) return;
    float m1x = stats[0], m1y = stats[1], m1z = stats[2];
    float Mxx = stats[3], Mxy = stats[4], Mxz = stats[5];
    float Myy = stats[6], Myz = stats[7], Mzz = stats[8];
    float w0 = W[c], w1 = W[HID + c], w2 = W[2 * HID + c];
    const float invn = 1.0f / (float)N_NODES;
    float m1w = m1x * w0 + m1y * w1 + m1z * w2;
    float mean = m1w * invn + b[c];
    float quad = w0 * w0 * Mxx + w1 * w1 * Myy + w2 * w2 * Mzz
               + 2.f * (w0 * w1 * Mxy + w0 * w2 * Mxz + w1 * w2 * Myz);
    float ex2 = quad * invn + 2.f * b[c] * m1w * invn + b[c] * b[c];
    float var = ex2 - mean * mean;
    float inv = rsqrtf(var + BN_EPS);
    float sc = gamma[c] * inv;
    float sh = beta[c] - mean * sc;
    cbuf[c] = w0 * sc;
    cbuf[HID + c] = w1 * sc;
    cbuf[2 * HID + c] = w2 * sc;
    cbuf[3 * HID + c] = b[c] * sc + sh;
}

// streaming output: y = rd*(S . Wsc_c) + shift_c, PReLU
__global__ void final_out_kernel(const float4* __restrict__ S4, const float* __restrict__ cbuf,
                                 const float* __restrict__ prelu, float* __restrict__ out) {
    int t = blockIdx.x * blockDim.x + threadIdx.x;
    if (t >= N_NODES * HID) return;
    int n = t >> 5, c = t & 31;
    float4 s = S4[n];
    float y = s.w * (s.x * cbuf[c] + s.y * cbuf[HID + c] + s.z * cbuf[2 * HID + c])
            + cbuf[3 * HID + c];
    float a = prelu[0];
    out[t] = y >= 0.f ? y : a * y;
}

// ---------------- launch ----------------

extern "C" void kernel_launch(void* const* d_in, const int* in_sizes, int n_in,
                              void* d_out, int out_size, void* d_ws, size_t ws_size,
                              hipStream_t stream) {
    const float* x     = (const float*)d_in[0];
    const int*   ei    = (const int*)d_in[1];   // [2, E]: src row then dst row
    const float* W     = (const float*)d_in[2];
    const float* b     = (const float*)d_in[3];
    const float* gamma = (const float*)d_in[4];
    const float* beta  = (const float*)d_in[5];
    const float* prelu = (const float*)d_in[6];

    const int* src = ei;
    const int* dst = ei + N_EDGES;
    char* ws = (char*)d_ws;

    // ---- ws layout, total 3,600,640 B ----
    // cnt   @ 0         int[100000]     (400,000)
    // stats @ 400,000   float[16]       (64)      <- memset covers [0, 400,064)
    // cbuf  @ 400,064   float[144]      (576)     (pad to 16B boundary at 400,640)
    // xd    @ 400,640   float4[100000]  (1.6 MB)
    // S4    @ 2,000,640 float4[100000]  (1.6 MB)
    int*    cnt   = (int*)(ws);
    float*  stats = (float*)(ws + 400000);
    float*  cbuf  = (float*)(ws + 400064);
    float4* xd    = (float4*)(ws + 400640);
    float4* S4    = (float4*)(ws + 2000640);
    float*  out   = (float*)d_out;

    hipMemsetAsync(ws, 0, 400064, stream);
    count_kernel<<<(N_EDGES + 255) / 256, 256, 0, stream>>>(dst, cnt);
    xd_kernel<<<(N_NODES + 255) / 256, 256, 0, stream>>>(x, cnt, xd, S4);
    scatter_kernel<<<(N_EDGES + 255) / 256, 256, 0, stream>>>(src, dst, xd, S4);
    stats_kernel<<<(N_NODES + 255) / 256, 256, 0, stream>>>(S4, stats);
    finalize_kernel<<<1, 64, 0, stream>>>(stats, W, b, gamma, beta, cbuf);
    final_out_kernel<<<(N_NODES * HID + 255) / 256, 256, 0, stream>>>(S4, cbuf, prelu, out);
}

// Round 5
// 142.872 us; speedup vs baseline: 2.7771x; 2.7771x over previous
//
#include <hip/hip_runtime.h>

#define N_NODES 100000
#define N_EDGES 1600000
#define HID 32
#define BN_EPS 1e-5f

#define EPB   4096                 // edges per bin block
#define NBLK  391                  // ceil(N_EDGES / EPB)
#define BSZ   512                  // dst nodes per bucket
#define NBUCK 196                  // ceil(N_NODES / BSZ)
#define SRC_MASK 0x1FFFFu

// ============================ binned path ============================

// Each block bins its contiguous 4096-edge slice by dst-bucket entirely in LDS,
// then writes the slice back coalesced (ordered by bucket) + run metadata.
// NO scattered global writes, NO global atomics.
__global__ void bin_kernel(const int* __restrict__ src, const int* __restrict__ dst,
                           unsigned* __restrict__ bbuf, int* __restrict__ blen,
                           int* __restrict__ boffs) {
    __shared__ int hist[NBUCK], offs[NBUCK], curs[NBUCK];
    __shared__ int sc[256];
    __shared__ unsigned stage[EPB];
    int tid = threadIdx.x, blk = blockIdx.x;
    int e0 = blk * EPB;
    int cnt = N_EDGES - e0; if (cnt > EPB) cnt = EPB;

    unsigned pk[EPB / 256];
    int bk[EPB / 256];
#pragma unroll
    for (int i = 0; i < EPB / 256; ++i) {
        int j = tid + i * 256;
        if (j < cnt) {
            int e = e0 + j;
            int s = src[e], d = dst[e];
            bk[i] = d >> 9;
            pk[i] = ((unsigned)(d & (BSZ - 1)) << 17) | (unsigned)s;
        } else bk[i] = -1;
    }
    for (int j = tid; j < NBUCK; j += 256) hist[j] = 0;
    __syncthreads();
#pragma unroll
    for (int i = 0; i < EPB / 256; ++i)
        if (bk[i] >= 0) atomicAdd(&hist[bk[i]], 1);
    __syncthreads();
    // Hillis-Steele inclusive scan over 256 (NBUCK padded with zeros)
    int h = (tid < NBUCK) ? hist[tid] : 0;
    sc[tid] = h;
    __syncthreads();
    for (int off = 1; off < 256; off <<= 1) {
        int v = (tid >= off) ? sc[tid - off] : 0;
        __syncthreads();
        sc[tid] += v;
        __syncthreads();
    }
    if (tid < NBUCK) { offs[tid] = sc[tid] - h; curs[tid] = sc[tid] - h; }
    __syncthreads();
#pragma unroll
    for (int i = 0; i < EPB / 256; ++i)
        if (bk[i] >= 0) {
            int p = atomicAdd(&curs[bk[i]], 1);
            stage[p] = pk[i];
        }
    __syncthreads();
    for (int j = tid; j < cnt; j += 256) bbuf[e0 + j] = stage[j];   // coalesced
    for (int j = tid; j < NBUCK; j += 256) {
        blen[j * NBLK + blk]  = hist[j];
        boffs[j * NBLK + blk] = e0 + offs[j];
    }
}

// Per bucket: local degree histogram from binned runs; write xd = (x*rd, rd)
__global__ void degxd_kernel(const unsigned* __restrict__ bbuf, const int* __restrict__ blen,
                             const int* __restrict__ boffs, const float* __restrict__ x,
                             float4* __restrict__ xd) {
    __shared__ int hist[BSZ];
    int tid = threadIdx.x, b = blockIdx.x;
    for (int j = tid; j < BSZ; j += 512) hist[j] = 0;
    __syncthreads();
    for (int r = tid; r < NBLK; r += 512) {
        int len = blen[b * NBLK + r];
        int off = boffs[b * NBLK + r];
        for (int k = 0; k < len; ++k) {
            unsigned p = bbuf[off + k];
            atomicAdd(&hist[p >> 17], 1);
        }
    }
    __syncthreads();
    int base = b << 9;
    for (int l = tid; l < BSZ; l += 512) {
        int n = base + l;
        if (n < N_NODES) {
            float rd = rsqrtf(1.0f + (float)hist[l]);
            xd[n] = make_float4(x[3 * n] * rd, x[3 * n + 1] * rd, x[3 * n + 2] * rd, rd);
        }
    }
}

// Per bucket: S[local] += xd[src] via LDS atomics; self term; write S4; fused 9-scalar stats
__global__ void accum_kernel(const unsigned* __restrict__ bbuf, const int* __restrict__ blen,
                             const int* __restrict__ boffs, const float4* __restrict__ xd,
                             float4* __restrict__ S4, float* __restrict__ stats) {
    __shared__ float S[BSZ * 3];
    __shared__ float ls[8][9];
    int tid = threadIdx.x, b = blockIdx.x;
    for (int j = tid; j < BSZ * 3; j += 512) S[j] = 0.f;
    __syncthreads();
    for (int r = tid; r < NBLK; r += 512) {
        int len = blen[b * NBLK + r];
        int off = boffs[b * NBLK + r];
        for (int k = 0; k < len; ++k) {
            unsigned p = bbuf[off + k];
            float4 v = xd[p & SRC_MASK];
            int l3 = (int)(p >> 17) * 3;
            atomicAdd(&S[l3 + 0], v.x);
            atomicAdd(&S[l3 + 1], v.y);
            atomicAdd(&S[l3 + 2], v.z);
        }
    }
    __syncthreads();
    int base = b << 9;
    float st[9];
#pragma unroll
    for (int q = 0; q < 9; ++q) st[q] = 0.f;
    for (int l = tid; l < BSZ; l += 512) {
        int n = base + l;
        if (n < N_NODES) {
            float4 self = xd[n];
            float sx = S[l * 3 + 0] + self.x;
            float sy = S[l * 3 + 1] + self.y;
            float sz = S[l * 3 + 2] + self.z;
            S4[n] = make_float4(sx, sy, sz, self.w);
            float ax = self.w * sx, ay = self.w * sy, az = self.w * sz;
            st[0] += ax; st[1] += ay; st[2] += az;
            st[3] += ax * ax; st[4] += ax * ay; st[5] += ax * az;
            st[6] += ay * ay; st[7] += ay * az; st[8] += az * az;
        }
    }
    for (int m = 1; m < 64; m <<= 1)
#pragma unroll
        for (int q = 0; q < 9; ++q) st[q] += __shfl_xor(st[q], m);
    int wave = tid >> 6;
    if ((tid & 63) == 0)
#pragma unroll
        for (int q = 0; q < 9; ++q) ls[wave][q] = st[q];
    __syncthreads();
    if (tid < 9) {
        float s = 0.f;
#pragma unroll
        for (int w = 0; w < 8; ++w) s += ls[w][tid];
        atomicAdd(&stats[tid], s);
    }
}

// fold BN scale/shift into W and b: cbuf = {W0*sc, W1*sc, W2*sc, b*sc + sh}
__global__ void finalize_kernel(const float* __restrict__ stats, const float* __restrict__ W,
                                const float* __restrict__ b, const float* __restrict__ gamma,
                                const float* __restrict__ beta, float* __restrict__ cbuf) {
    int c = threadIdx.x;
    if (c >= HID) return;
    float m1x = stats[0], m1y = stats[1], m1z = stats[2];
    float Mxx = stats[3], Mxy = stats[4], Mxz = stats[5];
    float Myy = stats[6], Myz = stats[7], Mzz = stats[8];
    float w0 = W[c], w1 = W[HID + c], w2 = W[2 * HID + c];
    const float invn = 1.0f / (float)N_NODES;
    float m1w = m1x * w0 + m1y * w1 + m1z * w2;
    float mean = m1w * invn + b[c];
    float quad = w0 * w0 * Mxx + w1 * w1 * Myy + w2 * w2 * Mzz
               + 2.f * (w0 * w1 * Mxy + w0 * w2 * Mxz + w1 * w2 * Myz);
    float ex2 = quad * invn + 2.f * b[c] * m1w * invn + b[c] * b[c];
    float var = ex2 - mean * mean;
    float inv = rsqrtf(var + BN_EPS);
    float sc = gamma[c] * inv;
    float sh = beta[c] - mean * sc;
    cbuf[c] = w0 * sc;
    cbuf[HID + c] = w1 * sc;
    cbuf[2 * HID + c] = w2 * sc;
    cbuf[3 * HID + c] = b[c] * sc + sh;
}

// streaming output: y = rd*(S . Wsc_c) + shift_c, PReLU
__global__ void final_out_kernel(const float4* __restrict__ S4, const float* __restrict__ cbuf,
                                 const float* __restrict__ prelu, float* __restrict__ out) {
    int t = blockIdx.x * blockDim.x + threadIdx.x;
    if (t >= N_NODES * HID) return;
    int n = t >> 5, c = t & 31;
    float4 s = S4[n];
    float y = s.w * (s.x * cbuf[c] + s.y * cbuf[HID + c] + s.z * cbuf[2 * HID + c])
            + cbuf[3 * HID + c];
    float a = prelu[0];
    out[t] = y >= 0.f ? y : a * y;
}

// ============================ fallback (round-4) path ============================

__global__ void fb_count_kernel(const int* __restrict__ dst, int* __restrict__ cnt) {
    int e = blockIdx.x * blockDim.x + threadIdx.x;
    if (e < N_EDGES) atomicAdd(&cnt[dst[e]], 1);
}

__global__ void fb_xd_kernel(const float* __restrict__ x, const int* __restrict__ cnt,
                             float4* __restrict__ xd, float4* __restrict__ S4) {
    int n = blockIdx.x * blockDim.x + threadIdx.x;
    if (n >= N_NODES) return;
    float rd = rsqrtf(1.0f + (float)cnt[n]);
    float4 v = make_float4(x[3 * n] * rd, x[3 * n + 1] * rd, x[3 * n + 2] * rd, rd);
    xd[n] = v;
    S4[n] = v;
}

__global__ void fb_scatter_kernel(const int* __restrict__ src, const int* __restrict__ dst,
                                  const float4* __restrict__ xd, float4* __restrict__ S4) {
    int e = blockIdx.x * blockDim.x + threadIdx.x;
    if (e >= N_EDGES) return;
    int s = src[e], d = dst[e];
    float4 v = xd[s];
    float* p = (float*)&S4[d];
    atomicAdd(p + 0, v.x);
    atomicAdd(p + 1, v.y);
    atomicAdd(p + 2, v.z);
}

__global__ void fb_stats_kernel(const float4* __restrict__ S4, float* __restrict__ stats) {
    __shared__ float ls[4][9];
    int tid = threadIdx.x;
    int n = blockIdx.x * blockDim.x + tid;
    float st[9];
#pragma unroll
    for (int q = 0; q < 9; ++q) st[q] = 0.f;
    if (n < N_NODES) {
        float4 s = S4[n];
        float ax = s.w * s.x, ay = s.w * s.y, az = s.w * s.z;
        st[0] = ax; st[1] = ay; st[2] = az;
        st[3] = ax * ax; st[4] = ax * ay; st[5] = ax * az;
        st[6] = ay * ay; st[7] = ay * az; st[8] = az * az;
    }
    for (int m = 1; m < 64; m <<= 1)
#pragma unroll
        for (int q = 0; q < 9; ++q) st[q] += __shfl_xor(st[q], m);
    int wave = tid >> 6;
    if ((tid & 63) == 0)
#pragma unroll
        for (int q = 0; q < 9; ++q) ls[wave][q] = st[q];
    __syncthreads();
    if (tid < 9) {
        float s = ls[0][tid] + ls[1][tid] + ls[2][tid] + ls[3][tid];
        atomicAdd(&stats[tid], s);
    }
}

// ============================ launch ============================

extern "C" void kernel_launch(void* const* d_in, const int* in_sizes, int n_in,
                              void* d_out, int out_size, void* d_ws, size_t ws_size,
                              hipStream_t stream) {
    const float* x     = (const float*)d_in[0];
    const int*   ei    = (const int*)d_in[1];   // [2, E]: src row then dst row
    const float* W     = (const float*)d_in[2];
    const float* b     = (const float*)d_in[3];
    const float* gamma = (const float*)d_in[4];
    const float* beta  = (const float*)d_in[5];
    const float* prelu = (const float*)d_in[6];

    const int* src = ei;
    const int* dst = ei + N_EDGES;
    char* ws = (char*)d_ws;
    float* out = (float*)d_out;

    // ---- ws layout (binned path), total 10,219,296 B ----
    // stats @ 0          float[16]              (64)
    // cbuf  @ 64         float[128]             (512)  -> pad to 576
    // bbuf  @ 640        u32[EPB*NBLK]          (6,406,144)
    // blen  @ 6,406,784  int[NBUCK*NBLK]        (306,544)
    // boffs @ 6,713,328  int[NBUCK*NBLK]        (306,544)
    // xd    @ 7,019,872+pad -> 7,019,872 is 16B-aligned? 7019872/16=438742 ✓
    // xd    @ 7,019,872  float4[100000]         (1,600,000)
    // S4    @ 8,619,872  float4[100000]         (1,600,000)
    const size_t NEEDED = 10219872;

    if (ws_size >= NEEDED) {
        float*    stats = (float*)(ws);
        float*    cbuf  = (float*)(ws + 64);
        unsigned* bbuf  = (unsigned*)(ws + 640);
        int*      blen  = (int*)(ws + 6406784);
        int*      boffs = (int*)(ws + 6713328);
        float4*   xd    = (float4*)(ws + 7019872);
        float4*   S4    = (float4*)(ws + 8619872);

        hipMemsetAsync(stats, 0, 64, stream);
        bin_kernel<<<NBLK, 256, 0, stream>>>(src, dst, bbuf, blen, boffs);
        degxd_kernel<<<NBUCK, 512, 0, stream>>>(bbuf, blen, boffs, x, xd);
        accum_kernel<<<NBUCK, 512, 0, stream>>>(bbuf, blen, boffs, xd, S4, stats);
        finalize_kernel<<<1, 64, 0, stream>>>(stats, W, b, gamma, beta, cbuf);
        final_out_kernel<<<(N_NODES * HID + 255) / 256, 256, 0, stream>>>(S4, cbuf, prelu, out);
    } else {
        // fallback: round-4 direct-atomic path (ws need ~3.6 MB)
        int*    cnt   = (int*)(ws);
        float*  stats = (float*)(ws + 400000);
        float*  cbuf  = (float*)(ws + 400064);
        float4* xd    = (float4*)(ws + 400640);
        float4* S4    = (float4*)(ws + 2000640);

        hipMemsetAsync(ws, 0, 400064, stream);
        fb_count_kernel<<<(N_EDGES + 255) / 256, 256, 0, stream>>>(dst, cnt);
        fb_xd_kernel<<<(N_NODES + 255) / 256, 256, 0, stream>>>(x, cnt, xd, S4);
        fb_scatter_kernel<<<(N_EDGES + 255) / 256, 256, 0, stream>>>(src, dst, xd, S4);
        fb_stats_kernel<<<(N_NODES + 255) / 256, 256, 0, stream>>>(S4, stats);
        finalize_kernel<<<1, 64, 0, stream>>>(stats, W, b, gamma, beta, cbuf);
        final_out_kernel<<<(N_NODES * HID + 255) / 256, 256, 0, stream>>>(S4, cbuf, prelu, out);
    }
}